// Round 6
// baseline (157.205 us; speedup 1.0000x reference)
//
#include <hip/hip_runtime.h>
#include <hip/hip_bf16.h>
#include <stdint.h>

// Problem constants
constexpr int NB = 8;     // batch
constexpr int NS = 1024;  // seq
constexpr int ND = 1024;  // model dim
constexpr int NH = 16;    // heads
constexpr int NDK = 64;   // head dim
constexpr int NT = NS / 64;  // 16 q-tiles of 64 rows

typedef __bf16 bf16_t;
typedef __attribute__((ext_vector_type(8))) __bf16 bf16x8;
typedef __attribute__((ext_vector_type(4))) __bf16 bf16x4;
typedef __attribute__((ext_vector_type(4))) float f32x4;

#define GLL16(g, s) __builtin_amdgcn_global_load_lds( \
    (const __attribute__((address_space(1))) void*)(g), \
    (__attribute__((address_space(3))) void*)(s), 16, 0, 0)

// ---------------- fp32 -> bf16 converts (fused launches) ----------------
__device__ __forceinline__ void cvt_body(const float* __restrict__ s,
                                         bf16_t* __restrict__ d, long n) {
  long i0 = (long)(blockIdx.x * blockDim.x + threadIdx.x) * 4;
  long step = (long)gridDim.x * blockDim.x * 4;
  for (long i = i0; i < n; i += step) {
    float4 f = *(const float4*)(s + i);
    bf16x4 o;
    o[0] = (bf16_t)f.x; o[1] = (bf16_t)f.y; o[2] = (bf16_t)f.z; o[3] = (bf16_t)f.w;
    *(bf16x4*)(d + i) = o;
  }
}

__global__ __launch_bounds__(256) void cvt3_kernel(const float* s0, bf16_t* d0,
                                                   const float* s1, bf16_t* d1,
                                                   const float* s2, bf16_t* d2, long n) {
  const float* s = blockIdx.y == 0 ? s0 : blockIdx.y == 1 ? s1 : s2;
  bf16_t* d = blockIdx.y == 0 ? d0 : blockIdx.y == 1 ? d1 : d2;
  cvt_body(s, d, n);
}

__global__ __launch_bounds__(256) void cvt4_kernel(const float* s0, bf16_t* d0,
                                                   const float* s1, bf16_t* d1,
                                                   const float* s2, bf16_t* d2,
                                                   const float* s3, bf16_t* d3, long n) {
  const float* s = blockIdx.y == 0 ? s0 : blockIdx.y == 1 ? s1 : blockIdx.y == 2 ? s2 : s3;
  bf16_t* d = blockIdx.y == 0 ? d0 : blockIdx.y == 1 ? d1 : blockIdx.y == 2 ? d2 : d3;
  cvt_body(s, d, n);
}

// ---------------- GEMM: C[M,N] = A[M,K] @ W[N,K]^T + bias ----------------
// 256x128 tile, 8 waves as 4M x 2N (per-wave 64x64 — square, fewer LDS reads),
// BK=64, mfma 16x16x32. Triple-buffered LDS (144 KB, 1 block/CU), prefetch
// distance 2 with GLLs interleaved INTO the compute phases, counted vmcnt(6)
// (never 0 mid-loop). Per K-tile: 2 staggered phases (kk=0,1), each
// {ds_read 8 frags + 3 GLLs -> barrier -> setprio(1) 16 MFMA setprio(0) ->
// barrier} so one wave's MFMA overlaps other waves' ds_reads (m201 pattern).
// XOR-swizzled 128B LDS rows w/ pre-swizzled global source (0 conflicts, R3+).
template<bool OUT_F32>
__device__ __forceinline__ void gemm_body(bf16_t* S,
                                          const bf16_t* __restrict__ A,
                                          const bf16_t* __restrict__ W,
                                          const float* __restrict__ bias,
                                          void* __restrict__ Cout,
                                          int M, int N, int K, int bx, int by) {
  const int tid = threadIdx.x;           // 0..511
  const int l = tid & 63, w = tid >> 6;  // 8 waves
  const int wr = w >> 1, wc = w & 1;     // 4M x 2N
  const int g = l >> 4, r = l & 15;
  const int m0 = by * 256, n0 = bx * 128;
  const int wbase = w * 512;             // wave-uniform LDS base (elements)

  auto stageA = [&](int q, int t, int it) {
    int idx = it * 512 + tid;
    int row = idx >> 3, c = (idx & 7) ^ (row & 7);
    GLL16(A + (size_t)(m0 + row) * K + (t << 6) + c * 8,
          S + q * 24576 + it * 4096 + wbase);
  };
  auto stageB = [&](int q, int t, int it) {
    int idx = it * 512 + tid;
    int row = idx >> 3, c = (idx & 7) ^ (row & 7);
    GLL16(W + (size_t)(n0 + row) * K + (t << 6) + c * 8,
          S + q * 24576 + 16384 + it * 4096 + wbase);
  };

  f32x4 acc[4][4] = {};
  const int NKT = K >> 6;

  // prologue: tiles 0 and 1 fully staged (12 GLLs in flight)
#pragma unroll
  for (int it = 0; it < 4; ++it) stageA(0, 0, it);
#pragma unroll
  for (int it = 0; it < 2; ++it) stageB(0, 0, it);
#pragma unroll
  for (int it = 0; it < 4; ++it) stageA(1, 1, it);
#pragma unroll
  for (int it = 0; it < 2; ++it) stageB(1, 1, it);

  int q = 0;
  for (int t = 0; t < NKT; ++t) {
    const bool pf = (t + 2 < NKT);
    int q2 = q + 2; if (q2 >= 3) q2 -= 3;

    // in-flight = tiles t,t+1 (6 each); retire tile t's
    if (t + 1 < NKT) asm volatile("s_waitcnt vmcnt(6)" ::: "memory");
    else             asm volatile("s_waitcnt vmcnt(0)" ::: "memory");
    __builtin_amdgcn_s_barrier();        // tile t visible to all waves

    const bf16_t* a_ = S + q * 24576;
    const bf16_t* b_ = a_ + 16384;

#pragma unroll
    for (int kk = 0; kk < 2; ++kk) {
      bf16x8 af[4], bw[4];
#pragma unroll
      for (int m = 0; m < 4; ++m) {
        int row = wr * 64 + m * 16 + r;
        af[m] = *(const bf16x8*)(a_ + row * 64 + (((kk * 4 + g) ^ (row & 7)) << 3));
      }
#pragma unroll
      for (int n = 0; n < 4; ++n) {
        int row = wc * 64 + n * 16 + r;
        bw[n] = *(const bf16x8*)(b_ + row * 64 + (((kk * 4 + g) ^ (row & 7)) << 3));
      }
      if (pf) {
        if (kk == 0) { stageA(q2, t + 2, 0); stageA(q2, t + 2, 1); stageA(q2, t + 2, 2); }
        else         { stageA(q2, t + 2, 3); stageB(q2, t + 2, 0); stageB(q2, t + 2, 1); }
      }
      __builtin_amdgcn_s_barrier();      // stagger: reads+stage issued
      __builtin_amdgcn_s_setprio(1);
#pragma unroll
      for (int m = 0; m < 4; ++m)
#pragma unroll
        for (int n = 0; n < 4; ++n)
          acc[m][n] = __builtin_amdgcn_mfma_f32_16x16x32_bf16(af[m], bw[n], acc[m][n], 0, 0, 0);
      __builtin_amdgcn_s_setprio(0);
      if (kk == 0) __builtin_amdgcn_s_barrier();  // close phase 0
      // phase 1's close = next iteration's top barrier
    }
    ++q; if (q >= 3) q -= 3;
  }

#pragma unroll
  for (int n = 0; n < 4; ++n) {
    int col = n0 + wc * 64 + n * 16 + r;
    float bv = bias[col];
#pragma unroll
    for (int m = 0; m < 4; ++m) {
      int row0 = m0 + wr * 64 + m * 16 + g * 4;
#pragma unroll
      for (int j = 0; j < 4; ++j) {
        float vv = acc[m][n][j] + bv;
        if (OUT_F32)
          ((float*)Cout)[(size_t)(row0 + j) * N + col] = vv;
        else
          ((bf16_t*)Cout)[(size_t)(row0 + j) * N + col] = (bf16_t)vv;
      }
    }
  }
}

// O-projection: grid 256 = exactly 1 round at 1 block/CU; XCD-grouped.
__global__ __launch_bounds__(512, 2) void gemm_bt(const bf16_t* __restrict__ A,
                                                  const bf16_t* __restrict__ W,
                                                  const float* __restrict__ bias,
                                                  float* __restrict__ Cout,
                                                  int M, int N, int K) {
  __shared__ bf16_t S[3 * 24576];
  const int o = blockIdx.x;
  const int xcd = o & 7, s = o >> 3;   // s in [0,32)
  const int bx = s & 7, u = s >> 3;    // u in [0,4)
  const int by = xcd + 8 * u;          // all bx of one by share an XCD
  gemm_body<true>(S, A, W, bias, (void*)Cout, M, N, K, bx, by);
}

// QKV: grid 768 = exactly 3 rounds at 1 block/CU; XCD-grouped.
__global__ __launch_bounds__(512, 2) void gemm_qkv(
    const bf16_t* A0, const bf16_t* W0, const float* b0, bf16_t* C0,
    const bf16_t* A1, const bf16_t* W1, const float* b1, bf16_t* C1,
    const bf16_t* A2, const bf16_t* W2, const float* b2, bf16_t* C2,
    int M, int N, int K) {
  __shared__ bf16_t S[3 * 24576];
  const int o = blockIdx.x;
  const int xcd = o & 7, s = o >> 3;   // s in [0,96)
  const int bx = s & 7, u = s >> 3;    // u in [0,12)
  const int zby = xcd + 8 * u;         // 0..95
  const int z = zby >> 5, by = zby & 31;
  const bf16_t* A = z == 0 ? A0 : z == 1 ? A1 : A2;
  const bf16_t* W = z == 0 ? W0 : z == 1 ? W1 : W2;
  const float* bb = z == 0 ? b0 : z == 1 ? b1 : b2;
  bf16_t* C = z == 0 ? C0 : z == 1 ? C1 : C2;
  gemm_body<false>(S, A, W, bb, (void*)C, M, N, K, bx, by);
}

// ---------------- causal flash attention (2-phase, swapped QK^T) ----------
// Swapped-operand QK^T: sacc = mfma(K, Q) = S^T, so lane (g,r) holds 16
// scores of ITS OWN q-row r (keys 16n+4g+j). Row softmax = in-register
// reduce + 2 shuffles (xor16/32); m,l are per-lane scalars. P stored as
// Pl[q][key] via 4x ds_write_b64. PV computed as O^T = V^T P^T (mfma(vf,pf))
// so the esc rescale and l-divide are lane-local. Scale 0.125*log2e folded
// into Q; exp2 direct; T13 defer-max (THR=8, log2 domain).
__global__ __launch_bounds__(256, 4) void attn_kernel(const bf16_t* __restrict__ Q1,
                                                      const bf16_t* __restrict__ K1,
                                                      const bf16_t* __restrict__ V1,
                                                      bf16_t* __restrict__ attn) {
  __shared__ bf16_t Kt[2][64 * 64];
  __shared__ bf16_t Vt[2][64 * 64];
  __shared__ bf16_t Pl[4][16 * 64];

  const int tid = threadIdx.x;
  const int l = tid & 63, w = tid >> 6;
  const int g = l >> 4, r = l & 15;

  // bijective XCD swizzle (nwg=1024): all blocks of a given (b,h) on one XCD.
  const int o = blockIdx.x;
  const int os = (o & 7) * 128 + (o >> 3);
  const int pair = os & 7, hb = os >> 3;
  const int h = hb & 15, b = hb >> 4;

  constexpr float SC = 0.18033688011112042f;  // 0.125 * log2(e)

  for (int ph = 0; ph < 2; ++ph) {
    const int qt = ph ? (NT - 1 - pair) : pair;
    const int qrow_g = qt * 64 + w * 16 + r;  // this lane's q-row (global)

    const bf16_t* qptr = Q1 + ((size_t)b * NS + qrow_g) * ND + h * 64;
    bf16x8 qf0 = *(const bf16x8*)(qptr + g * 8);
    bf16x8 qf1 = *(const bf16x8*)(qptr + 32 + g * 8);
#pragma unroll
    for (int i = 0; i < 8; ++i) {
      qf0[i] = (bf16_t)((float)qf0[i] * SC);
      qf1[i] = (bf16_t)((float)qf1[i] * SC);
    }

    float mrun = -1e30f, lrun = 0.f;
    f32x4 oacc[4] = {};

    __syncthreads();  // prior phase's readers done before we restage buffers

    // prologue: stage tile 0 into buffer 0
    bf16x8 vr0, vr1;
    {
#pragma unroll
      for (int it = 0; it < 2; ++it) {
        int idx = it * 256 + tid;
        int key = idx >> 3;
        int dkg = ((idx & 7) ^ (key & 7)) << 3;
        GLL16(K1 + ((size_t)b * NS + key) * ND + h * 64 + dkg,
              &Kt[0][(it * 256 + w * 64) * 8]);
      }
      vr0 = *(const bf16x8*)(V1 + ((size_t)b * NS + l) * ND + h * 64 + w * 8);
      vr1 = *(const bf16x8*)(V1 + ((size_t)b * NS + l) * ND + h * 64 + (4 + w) * 8);
    }

    for (int kt = 0; kt <= qt; ++kt) {
      const int p = kt & 1;
      const int k0 = kt * 64;

      // commit V regs -> Vt[p] (transposed + swizzled)
#pragma unroll
      for (int it = 0; it < 2; ++it) {
        int dkb = (it * 4 + w) * 8;
#pragma unroll
        for (int jj = 0; jj < 8; ++jj) {
          int dk = dkb + jj;
          int boff = dk * 128 + ((l * 2) ^ ((dk & 7) << 4));
          *(bf16_t*)((char*)Vt[p] + boff) = (it ? vr1 : vr0)[jj];
        }
      }
      __syncthreads();  // tile kt fully staged & visible

      // prefetch tile kt+1 into buffers p^1 (lands during compute below)
      if (kt < qt) {
        const int k0n = k0 + 64;
#pragma unroll
        for (int it = 0; it < 2; ++it) {
          int idx = it * 256 + tid;
          int key = idx >> 3;
          int dkg = ((idx & 7) ^ (key & 7)) << 3;
          GLL16(K1 + ((size_t)b * NS + k0n + key) * ND + h * 64 + dkg,
                &Kt[p ^ 1][(it * 256 + w * 64) * 8]);
        }
        vr0 = *(const bf16x8*)(V1 + ((size_t)b * NS + k0n + l) * ND + h * 64 + w * 8);
        vr1 = *(const bf16x8*)(V1 + ((size_t)b * NS + k0n + l) * ND + h * 64 + (4 + w) * 8);
      }

      // --- QK^T (swapped): sacc[n] rows = keys 16n+4g+j, col = q-row r
      f32x4 sacc[4] = {};
      __builtin_amdgcn_s_setprio(1);
#pragma unroll
      for (int n = 0; n < 4; ++n) {
        int key = n * 16 + r;
#pragma unroll
        for (int kk = 0; kk < 2; ++kk) {
          int dk2 = kk * 32 + g * 8;
          int boff = key * 128 + ((dk2 * 2) ^ ((key & 7) << 4));
          bf16x8 kf = *(const bf16x8*)((char*)Kt[p] + boff);
          sacc[n] = __builtin_amdgcn_mfma_f32_16x16x32_bf16(kf, kk == 0 ? qf0 : qf1, sacc[n], 0, 0, 0);
        }
      }
      __builtin_amdgcn_s_setprio(0);

      // --- causal mask (diag tile only): key = k0+16n+4g+j vs qrow_g
      if (kt == qt) {
#pragma unroll
        for (int n = 0; n < 4; ++n)
#pragma unroll
          for (int j = 0; j < 4; ++j)
            if (k0 + n * 16 + g * 4 + j > qrow_g) sacc[n][j] = -1e30f;
      }

      // --- per-lane max over 16, then 2 cross-lane shuffles
      float mx;
      {
        float t0 = fmaxf(fmaxf(sacc[0][0], sacc[0][1]), fmaxf(sacc[0][2], sacc[0][3]));
        float t1 = fmaxf(fmaxf(sacc[1][0], sacc[1][1]), fmaxf(sacc[1][2], sacc[1][3]));
        float t2 = fmaxf(fmaxf(sacc[2][0], sacc[2][1]), fmaxf(sacc[2][2], sacc[2][3]));
        float t3 = fmaxf(fmaxf(sacc[3][0], sacc[3][1]), fmaxf(sacc[3][2], sacc[3][3]));
        mx = fmaxf(fmaxf(t0, t1), fmaxf(t2, t3));
      }
      mx = fmaxf(mx, __shfl_xor(mx, 16));
      mx = fmaxf(mx, __shfl_xor(mx, 32));

      // --- T13 defer-max: only rescale when max grew past THR (log2 units)
      if (!__all(mx <= mrun + 8.0f)) {
        float m_new = fmaxf(mrun, mx);
        float esc = __builtin_amdgcn_exp2f(mrun - m_new);
        mrun = m_new;
        lrun *= esc;
#pragma unroll
        for (int n = 0; n < 4; ++n)
#pragma unroll
          for (int j = 0; j < 4; ++j) oacc[n][j] *= esc;
      }

      // --- P = exp2(S - m), store P[q=r][key] (4x ds_write_b64), row-sum
      float rsum = 0.f;
#pragma unroll
      for (int n = 0; n < 4; ++n) {
        bf16x4 p4;
#pragma unroll
        for (int j = 0; j < 4; ++j) {
          float pe = __builtin_amdgcn_exp2f(sacc[n][j] - mrun);
          rsum += pe;
          p4[j] = (bf16_t)pe;
        }
        *(bf16x4*)((char*)Pl[w] + r * 128 + ((n * 32 + g * 8) ^ ((r & 7) << 4))) = p4;
      }
      rsum += __shfl_xor(rsum, 16);
      rsum += __shfl_xor(rsum, 32);
      lrun += rsum;

      // --- PV: O^T = V^T P^T; lane-local rescale/divide
      __builtin_amdgcn_s_setprio(1);
#pragma unroll
      for (int kk = 0; kk < 2; ++kk) {
        bf16x8 pf = *(const bf16x8*)((char*)Pl[w] + r * 128 + ((kk * 64 + g * 16) ^ ((r & 7) << 4)));
#pragma unroll
        for (int n = 0; n < 4; ++n) {
          int dkr = n * 16 + r;
          bf16x8 vf = *(const bf16x8*)((char*)Vt[p] + dkr * 128 + ((kk * 64 + g * 16) ^ ((r & 7) << 4)));
          oacc[n] = __builtin_amdgcn_mfma_f32_16x16x32_bf16(vf, pf, oacc[n], 0, 0, 0);
        }
      }
      __builtin_amdgcn_s_setprio(0);
    }  // kt

    // epilogue: O[q=r][dk=16n+4g+j] /= l; 4x 8B stores
    float linv = 1.0f / lrun;
#pragma unroll
    for (int n = 0; n < 4; ++n) {
      bf16x4 o4;
#pragma unroll
      for (int j = 0; j < 4; ++j) o4[j] = (bf16_t)(oacc[n][j] * linv);
      *(bf16x4*)(attn + ((size_t)b * NS + qrow_g) * ND + h * 64 + n * 16 + g * 4) = o4;
    }
  }  // ph
}

// ---------------- launch ----------------
extern "C" void kernel_launch(void* const* d_in, const int* in_sizes, int n_in,
                              void* d_out, int out_size, void* d_ws, size_t ws_size,
                              hipStream_t stream) {
  const float* q  = (const float*)d_in[0];
  const float* k  = (const float*)d_in[1];
  const float* v  = (const float*)d_in[2];
  // d_in[3] = mask (int32 tril, implemented analytically)
  const float* Wq = (const float*)d_in[4];
  const float* bq = (const float*)d_in[5];
  const float* Wk = (const float*)d_in[6];
  const float* bk = (const float*)d_in[7];
  const float* Wv = (const float*)d_in[8];
  const float* bv = (const float*)d_in[9];
  const float* Wo = (const float*)d_in[10];
  const float* bo = (const float*)d_in[11];
  float* out = (float*)d_out;

  const size_t NX = (size_t)NB * NS * ND;  // 8388608
  const size_t NW = (size_t)ND * ND;       // 1048576
  char* ws = (char*)d_ws;
  size_t off = 0;
  auto alloc = [&](size_t bytes) {
    char* p = ws + off;
    off += (bytes + 255) & ~(size_t)255;
    return p;
  };
  bf16_t* xq  = (bf16_t*)alloc(NX * 2);
  bf16_t* xk  = (bf16_t*)alloc(NX * 2);
  bf16_t* xv  = (bf16_t*)alloc(NX * 2);
  bf16_t* wqb = (bf16_t*)alloc(NW * 2);
  bf16_t* wkb = (bf16_t*)alloc(NW * 2);
  bf16_t* wvb = (bf16_t*)alloc(NW * 2);
  bf16_t* wob = (bf16_t*)alloc(NW * 2);
  bf16_t* q1  = (bf16_t*)alloc(NX * 2);
  bf16_t* k1  = (bf16_t*)alloc(NX * 2);
  bf16_t* v1  = (bf16_t*)alloc(NX * 2);
  bf16_t* at  = xq;  // xq dead after QKV GEMMs; reuse for attn output

  dim3 blk(256);
  cvt3_kernel<<<dim3(1024, 3), blk, 0, stream>>>(q, xq, k, xk, v, xv, (long)NX);
  cvt4_kernel<<<dim3(128, 4), blk, 0, stream>>>(Wq, wqb, Wk, wkb, Wv, wvb, Wo, wob, (long)NW);

  gemm_qkv<<<dim3(768), dim3(512), 0, stream>>>(
      xq, wqb, bq, q1, xk, wkb, bk, k1, xv, wvb, bv, v1, NB * NS, ND, ND);

  attn_kernel<<<dim3((NT / 2) * NH * NB), blk, 0, stream>>>(q1, k1, v1, at);

  gemm_bt<<<dim3(256), dim3(512), 0, stream>>>(at, wob, bo, out, NB * NS, ND, ND);
}